// Round 7
// baseline (87.008 us; speedup 1.0000x reference)
//
#include <hip/hip_runtime.h>
#include <hip/hip_bf16.h>

#define NB 8
#define NT 2048
#define NC 1024
#define NH 64

typedef __attribute__((ext_vector_type(8))) short bf16x8;
typedef __attribute__((ext_vector_type(4))) short bf16x4;
typedef __attribute__((ext_vector_type(4))) float f32x4;

__device__ __forceinline__ unsigned short f2bf(float f) {
  __hip_bfloat16 h = __float2bfloat16(f);
  return __builtin_bit_cast(unsigned short, h);
}

__device__ __forceinline__ f32x4 mfma32(bf16x8 a, bf16x8 b, f32x4 c) {
  return __builtin_amdgcn_mfma_f32_16x16x32_bf16(a, b, c, 0, 0, 0);
}

#if __has_builtin(__builtin_amdgcn_mfma_f32_16x16x16bf16_1k)
__device__ __forceinline__ f32x4 mfma16(bf16x4 a, bf16x4 b, f32x4 c) {
  return __builtin_amdgcn_mfma_f32_16x16x16bf16_1k(a, b, c, 0, 0, 0);
}
#else
__device__ __forceinline__ f32x4 mfma16(bf16x4 a, bf16x4 b, f32x4 c) {
  asm volatile("v_mfma_f32_16x16x16_bf16 %0, %1, %2, %0\n\ts_nop 7"
               : "+v"(c) : "v"(a), "v"(b));
  return c;
}
#endif

// async global->LDS, 16B per lane, wave-uniform LDS base + lane*16
__device__ __forceinline__ void stage16(const float* src, char* lds_base) {
#if __has_builtin(__builtin_amdgcn_global_load_lds)
  __builtin_amdgcn_global_load_lds(
      (const __attribute__((address_space(1))) void*)src,
      (__attribute__((address_space(3))) void*)lds_base, 16, 0, 0);
#endif
}

// ---------------------------------------------------------------------------
// Kernel 0: weight transpose+convert. W[1024][64] f32 -> Wt[64][1024] bf16.
// Folds softmax scale * log2(e) into Wq so attention can use exp2 directly.
// ---------------------------------------------------------------------------
__global__ __launch_bounds__(256) void wt_kernel(const float* __restrict__ Wq,
                                                 const float* __restrict__ Wk,
                                                 const float* __restrict__ Wv,
                                                 unsigned short* __restrict__ Wt) {
  __shared__ float lds[64][65];
  int wi = blockIdx.x >> 4, kt = blockIdx.x & 15;
  const float* W = (wi == 0) ? Wq : ((wi == 1) ? Wk : Wv);
  float scale = (wi == 0) ? 0.18033688011112043f : 1.0f;  // 0.125 * log2(e)
  int tid = threadIdx.x;
#pragma unroll
  for (int i = 0; i < 16; ++i) {
    int idx = tid + i * 256;
    lds[idx >> 6][idx & 63] = W[(size_t)(kt * 64 + (idx >> 6)) * NH + (idx & 63)] * scale;
  }
  __syncthreads();
#pragma unroll
  for (int i = 0; i < 16; ++i) {
    int idx = tid + i * 256;
    int n = idx >> 6, kk = idx & 63;
    Wt[(size_t)(wi * 64 + n) * NC + kt * 64 + kk] = f2bf(lds[kk][n]);
  }
}

// ---------------------------------------------------------------------------
// Kernel 1: fused QKV projection, v6.
// 1024 blocks x 256 thr (4 waves). Block = 16 rows, LDS 19KB -> 8 blocks/CU
// = 32 waves/CU: eight desynchronized pipelines per CU hide each phase's
// barrier drain. x staged raw f32 via global_load_lds (granule-XOR swizzle
// on pre-swizzled source; LDS dest linear), BK=128, 8 phases, double-buffered
// 2x8KB, one barrier/phase. f32->bf16 folded into A-frag read. Wave w owns
// output cols [16w,16w+16) of q,k,v: per K-step 2 ds_read_b128 + 3 x 16B
// weight loads + 3 MFMA.
// ---------------------------------------------------------------------------
__global__ __launch_bounds__(256) void proj_kernel(const float* __restrict__ x,
                                                   const unsigned short* __restrict__ Wt,
                                                   unsigned short* __restrict__ qo,
                                                   unsigned short* __restrict__ ko,
                                                   unsigned short* __restrict__ vo) {
  __shared__ __align__(16) char xs2[2][8192];   // 16 rows x 128 f32 each
  __shared__ __align__(16) unsigned short vlds[64][24];

  int tid = threadIdx.x;
  int lane = tid & 63, w = tid >> 6;
  int ln = lane & 15, g = lane >> 4;
  int row0 = blockIdx.x * 16;

  int nc = w * 16 + ln;
  const unsigned short* wpq = Wt + (size_t)(0 * 64 + nc) * NC + g * 8;
  const unsigned short* wpk = Wt + (size_t)(1 * 64 + nc) * NC + g * 8;
  const unsigned short* wpv = Wt + (size_t)(2 * 64 + nc) * NC + g * 8;

  // staging: wave w stages rows [4w,4w+4); instr i covers rows 4w+2i,+1.
  // source col pre-swizzled: granule gcol ^ (row&7).
  int srowi[2], gsrc[2];
#pragma unroll
  for (int i = 0; i < 2; ++i) {
    srowi[i] = w * 4 + i * 2 + (lane >> 5);
    gsrc[i] = ((lane & 31) ^ (srowi[i] & 7)) << 2;   // float col
  }

  f32x4 acc[3];
#pragma unroll
  for (int j = 0; j < 3; ++j) acc[j] = (f32x4){0.f, 0.f, 0.f, 0.f};

  // prologue: stage phase 0 into buf 0
#pragma unroll
  for (int i = 0; i < 2; ++i)
    stage16(x + (size_t)(row0 + srowi[i]) * NC + gsrc[i],
            xs2[0] + (w * 4 + i * 2) * 512);
  __syncthreads();

#pragma unroll 1
  for (int p = 0; p < 8; ++p) {
    // stage phase p+1 into the other buffer (its old readers passed barrier)
    if (p < 7) {
#pragma unroll
      for (int i = 0; i < 2; ++i)
        stage16(x + (size_t)(row0 + srowi[i]) * NC + (p + 1) * 128 + gsrc[i],
                xs2[(p + 1) & 1] + (w * 4 + i * 2) * 512);
    }
    // compute phase p from buf[p&1]
    const char* bufc = xs2[p & 1];
#pragma unroll
    for (int c0 = 0; c0 < 128; c0 += 32) {
      int blk0 = (c0 >> 2) + g * 2;
      int by0 = ln * 512 + ((blk0 ^ (ln & 7)) << 4);
      int by1 = ln * 512 + (((blk0 + 1) ^ (ln & 7)) << 4);
      f32x4 lo = *(const f32x4*)(bufc + by0);
      f32x4 hi = *(const f32x4*)(bufc + by1);
      bf16x8 a;
#pragma unroll
      for (int j = 0; j < 4; ++j) {
        a[j] = (short)f2bf(lo[j]);
        a[4 + j] = (short)f2bf(hi[j]);
      }
      int kg = p * 128 + c0;
      bf16x8 bq = *(const bf16x8*)(wpq + kg);
      bf16x8 bk = *(const bf16x8*)(wpk + kg);
      bf16x8 bv = *(const bf16x8*)(wpv + kg);
      acc[0] = mfma32(a, bq, acc[0]);
      acc[1] = mfma32(a, bk, acc[1]);
      acc[2] = mfma32(a, bv, acc[2]);
    }
    __syncthreads();   // drains staging vmcnt; buf[(p+1)&1] ready
  }

  // ---- epilogue: q,k direct; v via LDS transpose
#pragma unroll
  for (int r = 0; r < 4; ++r) {
    int row = row0 + g * 4 + r;
    qo[(size_t)row * NH + nc] = f2bf(acc[0][r]);
    ko[(size_t)row * NH + nc] = f2bf(acc[1][r]);
    vlds[nc][g * 4 + r] = f2bf(acc[2][r]);
  }
  __syncthreads();
  if (tid < 128) {
    int b = row0 / NT, t0b = row0 % NT;
    int hh = tid >> 1, ts = (tid & 1) * 8;
    *(bf16x8*)(vo + (size_t)(b * NH + hh) * NT + t0b + ts) = *(const bf16x8*)&vlds[hh][ts];
  }
}

// ---------------------------------------------------------------------------
// Kernel 2: causal flash attention, v7. Swapped QK^T chains into PV's
// B-operand with zero shuffles. Wave = 32 queries (two 16-q subtiles sharing
// K/V). 512 blocks x 256 thr = 2 blocks/CU, 2 waves/SIMD. Block = one 32-q
// tile; folded balance map (b=bid&7 per-XCD batch residency; s=bid>>3,
// qtile = s<32 ? s : 95-s -> each CU's two slots sum to constant work).
// NEW: V loads hoisted above softmax; next chunk's K prefetched under
// softmax/PV. 4-way key-split, wave-0 fold, defer-rescale THR=8.
// ---------------------------------------------------------------------------
__global__ __launch_bounds__(256) void attn_kernel(const unsigned short* __restrict__ qw,
                                                   const unsigned short* __restrict__ kw,
                                                   const unsigned short* __restrict__ vw,
                                                   float* __restrict__ out) {
  __shared__ float mbuf[3][64][40];
  __shared__ float olds[32][68];

  int tid = threadIdx.x;
  int lane = tid & 63, ks = tid >> 6;
  int ln = lane & 15, g = lane >> 4;
  int bid = blockIdx.x;
  int b = bid & 7;
  int s = bid >> 3;                       // 0..63
  int qtile = (s < 32) ? s : 95 - s;      // folded: CU slot pair sums 63
  int t0 = qtile * 32;
  int tqA = t0 + ln, tqB = t0 + 16 + ln;

  const unsigned short* qpA = qw + (size_t)(b * NT + tqA) * NH + g * 8;
  const unsigned short* qpB = qw + (size_t)(b * NT + tqB) * NH + g * 8;
  bf16x8 qa0 = *(const bf16x8*)(qpA);
  bf16x8 qa1 = *(const bf16x8*)(qpA + 32);
  bf16x8 qb0 = *(const bf16x8*)(qpB);
  bf16x8 qb1 = *(const bf16x8*)(qpB + 32);

  const unsigned short* kb = kw + (size_t)b * NT * NH + g * 8;
  const unsigned short* vb = vw + (size_t)b * NH * NT;

  f32x4 oaccA[4], oaccB[4];
#pragma unroll
  for (int i = 0; i < 4; ++i) {
    oaccA[i] = (f32x4){0.f, 0.f, 0.f, 0.f};
    oaccB[i] = (f32x4){0.f, 0.f, 0.f, 0.f};
  }
  float mA = -1e30f, lA = 0.f, mB = -1e30f, lB = 0.f;

  // prefetch first chunk's K (always in-bounds: ks*64 <= 192 < NT)
  bf16x8 kc0[4], kc1[4];
#pragma unroll
  for (int st = 0; st < 4; ++st) {
    const unsigned short* kp = kb + (size_t)(ks * 64 + st * 16 + ln) * NH;
    kc0[st] = *(const bf16x8*)(kp);
    kc1[st] = *(const bf16x8*)(kp + 32);
  }

  int send = t0 + 32;
#pragma unroll 1
  for (int s0 = ks * 64; s0 < send; s0 += 256) {
    // ---- V loads early (independent of softmax)
    bf16x4 va[4][4];
#pragma unroll
    for (int hf = 0; hf < 4; ++hf) {
      const unsigned short* vp = vb + (size_t)(hf * 16 + ln) * NT + s0 + g * 4;
#pragma unroll
      for (int st = 0; st < 4; ++st) va[hf][st] = *(const bf16x4*)(vp + st * 16);
    }
    // ---- S^T = K x Q^T for both q-subtiles (K regs shared)
    f32x4 sA[4], sB[4];
#pragma unroll
    for (int st = 0; st < 4; ++st) {
      f32x4 a = (f32x4){0.f, 0.f, 0.f, 0.f};
      a = mfma32(kc0[st], qa0, a);
      a = mfma32(kc1[st], qa1, a);
      sA[st] = a;
      f32x4 c = (f32x4){0.f, 0.f, 0.f, 0.f};
      c = mfma32(kc0[st], qb0, c);
      c = mfma32(kc1[st], qb1, c);
      sB[st] = c;
    }
    // ---- prefetch next chunk's K (hidden under softmax + PV)
    if (s0 + 256 < send) {
#pragma unroll
      for (int st = 0; st < 4; ++st) {
        const unsigned short* kp = kb + (size_t)(s0 + 256 + st * 16 + ln) * NH;
        kc0[st] = *(const bf16x8*)(kp);
        kc1[st] = *(const bf16x8*)(kp + 32);
      }
    }
    // ---- causal masks (wave-uniform outer branches)
    if (s0 + 63 > t0) {
#pragma unroll
      for (int st = 0; st < 4; ++st)
#pragma unroll
        for (int r = 0; r < 4; ++r)
          if (s0 + st * 16 + g * 4 + r > tqA) sA[st][r] = -1e30f;
    }
    if (s0 + 63 > t0 + 16) {
#pragma unroll
      for (int st = 0; st < 4; ++st)
#pragma unroll
        for (int r = 0; r < 4; ++r)
          if (s0 + st * 16 + g * 4 + r > tqB) sB[st][r] = -1e30f;
    }
    // ---- online softmax A (base-2, deferred rescale)
    float tmax = -1e30f;
#pragma unroll
    for (int st = 0; st < 4; ++st)
#pragma unroll
      for (int r = 0; r < 4; ++r) tmax = fmaxf(tmax, sA[st][r]);
    tmax = fmaxf(tmax, __shfl_xor(tmax, 16));
    tmax = fmaxf(tmax, __shfl_xor(tmax, 32));
    if (__any(tmax > mA + 8.f)) {
      float mnew = fmaxf(mA, tmax);
      float sfac = exp2f(mA - mnew);
      lA *= sfac;
#pragma unroll
      for (int hf = 0; hf < 4; ++hf)
#pragma unroll
        for (int r = 0; r < 4; ++r) oaccA[hf][r] *= sfac;
      mA = mnew;
    }
    float psum = 0.f;
    bf16x4 pA[4];
#pragma unroll
    for (int st = 0; st < 4; ++st)
#pragma unroll
      for (int r = 0; r < 4; ++r) {
        float p = exp2f(sA[st][r] - mA);
        psum += p;
        pA[st][r] = (short)f2bf(p);
      }
    psum += __shfl_xor(psum, 16);
    psum += __shfl_xor(psum, 32);
    lA += psum;
    // ---- online softmax B
    tmax = -1e30f;
#pragma unroll
    for (int st = 0; st < 4; ++st)
#pragma unroll
      for (int r = 0; r < 4; ++r) tmax = fmaxf(tmax, sB[st][r]);
    tmax = fmaxf(tmax, __shfl_xor(tmax, 16));
    tmax = fmaxf(tmax, __shfl_xor(tmax, 32));
    if (__any(tmax > mB + 8.f)) {
      float mnew = fmaxf(mB, tmax);
      float sfac = exp2f(mB - mnew);
      lB *= sfac;
#pragma unroll
      for (int hf = 0; hf < 4; ++hf)
#pragma unroll
        for (int r = 0; r < 4; ++r) oaccB[hf][r] *= sfac;
      mB = mnew;
    }
    psum = 0.f;
    bf16x4 pB[4];
#pragma unroll
    for (int st = 0; st < 4; ++st)
#pragma unroll
      for (int r = 0; r < 4; ++r) {
        float p = exp2f(sB[st][r] - mB);
        psum += p;
        pB[st][r] = (short)f2bf(p);
      }
    psum += __shfl_xor(psum, 16);
    psum += __shfl_xor(psum, 32);
    lB += psum;

    // ---- PV from preloaded V regs (shared by both q-subtiles)
#pragma unroll
    for (int hf = 0; hf < 4; ++hf)
#pragma unroll
      for (int st = 0; st < 4; ++st) {
        oaccA[hf] = mfma16(va[hf][st], pA[st], oaccA[hf]);
        oaccB[hf] = mfma16(va[hf][st], pB[st], oaccB[hf]);
      }
  }

  // ---- fold the 4 key-split partials (wave 0 accumulates)
  if (ks) {
    float* d = mbuf[ks - 1][lane];
    d[0] = mA; d[1] = lA;
    d[18] = mB; d[19] = lB;
#pragma unroll
    for (int hf = 0; hf < 4; ++hf)
#pragma unroll
      for (int r = 0; r < 4; ++r) {
        d[2 + hf * 4 + r] = oaccA[hf][r];
        d[20 + hf * 4 + r] = oaccB[hf][r];
      }
  }
  __syncthreads();
  if (ks == 0) {
#pragma unroll
    for (int j = 0; j < 3; ++j) {
      const float* d = mbuf[j][lane];
      float mo = d[0], lo = d[1];
      float mx = fmaxf(mA, mo);
      float fS = exp2f(mA - mx), fO = exp2f(mo - mx);
      lA = lA * fS + lo * fO;
#pragma unroll
      for (int hf = 0; hf < 4; ++hf)
#pragma unroll
        for (int r = 0; r < 4; ++r)
          oaccA[hf][r] = oaccA[hf][r] * fS + d[2 + hf * 4 + r] * fO;
      mA = mx;
      mo = d[18]; lo = d[19];
      mx = fmaxf(mB, mo);
      fS = exp2f(mB - mx); fO = exp2f(mo - mx);
      lB = lB * fS + lo * fO;
#pragma unroll
      for (int hf = 0; hf < 4; ++hf)
#pragma unroll
        for (int r = 0; r < 4; ++r)
          oaccB[hf][r] = oaccB[hf][r] * fS + d[20 + hf * 4 + r] * fO;
      mB = mx;
    }
    float invA = 1.f / lA, invB = 1.f / lB;
#pragma unroll
    for (int hf = 0; hf < 4; ++hf)
#pragma unroll
      for (int r = 0; r < 4; ++r) {
        olds[ln][hf * 16 + g * 4 + r] = oaccA[hf][r] * invA;
        olds[16 + ln][hf * 16 + g * 4 + r] = oaccB[hf][r] * invB;
      }
  }
  __syncthreads();
  // ---- transposed store out[b][t][h]
  if (tid < 128) {
    int tl = tid >> 2, h0 = (tid & 3) * 16;
    size_t obase = (size_t)(b * NT + t0 + tl) * NH + h0;
#pragma unroll
    for (int vv = 0; vv < 4; ++vv) {
      float4 t4 = make_float4(olds[tl][h0 + vv * 4 + 0], olds[tl][h0 + vv * 4 + 1],
                              olds[tl][h0 + vv * 4 + 2], olds[tl][h0 + vv * 4 + 3]);
      *(float4*)(out + obase + vv * 4) = t4;
    }
  }
}

// ---------------------------------------------------------------------------
extern "C" void kernel_launch(void* const* d_in, const int* in_sizes, int n_in,
                              void* d_out, int out_size, void* d_ws, size_t ws_size,
                              hipStream_t stream) {
  const float* x  = (const float*)d_in[0];
  const float* Wq = (const float*)d_in[1];
  const float* Wk = (const float*)d_in[2];
  const float* Wv = (const float*)d_in[3];
  float* out = (float*)d_out;

  unsigned short* Wt = (unsigned short*)d_ws;
  unsigned short* q  = (unsigned short*)((char*)d_ws + (1 << 19));
  unsigned short* k  = q + (size_t)NB * NT * NH;
  unsigned short* v  = k + (size_t)NB * NT * NH;

  wt_kernel<<<48, 256, 0, stream>>>(Wq, Wk, Wv, Wt);
  proj_kernel<<<(NB * NT) / 16, 256, 0, stream>>>(x, Wt, q, k, v);
  attn_kernel<<<512, 256, 0, stream>>>(q, k, v, out);
}